// Round 2
// baseline (130.189 us; speedup 1.0000x reference)
//
#include <hip/hip_runtime.h>
#include <hip/hip_bf16.h>

#define B_ 1024
#define IN_ 512
#define OUT_ 512
#define BTILE 64
#define OTILE 32
#define ITILE 8
#define KSPLIT 16
#define KCHUNK (IN_ / KSPLIT)          // 32 i's per block = one MFMA K
#define NCHUNKS (KCHUNK / ITILE)       // 4 staging chunks
#define XSTRIDE 68    // BTILE + 4 pad; staging writes exactly 2-way (free)
#define ASTRIDE 40    // bf16 per sA/wB row = 80 B (16B-aligned); rows 2-way banks (free)

typedef float v2f   __attribute__((ext_vector_type(2)));
typedef float f32x4 __attribute__((ext_vector_type(4)));
typedef short s16x8 __attribute__((ext_vector_type(8)));   // 8 bf16 = 4 VGPRs
#define PKFMA(a, b, c) __builtin_elementwise_fma((v2f)(a), (v2f)(b), (v2f)(c))

__device__ __forceinline__ unsigned short f2bf(float f) {
    union { float f; unsigned int u; } v; v.f = f;
    unsigned int b = v.u + 0x7FFFu + ((v.u >> 16) & 1u);   // RNE
    return (unsigned short)(b >> 16);
}
__device__ __forceinline__ float fast_exp2(float x) {
#if __has_builtin(__builtin_amdgcn_exp2f)
    return __builtin_amdgcn_exp2f(x);
#else
    return __exp2f(x);
#endif
}
__device__ __forceinline__ float fast_log2(float x) {
#if __has_builtin(__builtin_amdgcn_logf)
    return __builtin_amdgcn_logf(x);
#else
    return __log2f(x);
#endif
}
__device__ __forceinline__ float fast_cos_rev(float x) {  // cos(2*pi*x), revolutions
#if __has_builtin(__builtin_amdgcn_cosf)
    return __builtin_amdgcn_cosf(x);   // ~12 busy-cyc/wave64 measured (R6/R14 back-solves);
                                       // poly replacement measured WORSE (R15)
#else
    return __cosf(x * 6.2831853071795864f);
#endif
}
__device__ __forceinline__ float fast_rcp(float x) {
#if __has_builtin(__builtin_amdgcn_rcpf)
    return __builtin_amdgcn_rcpf(x);
#else
    return 1.0f / x;
#endif
}

__global__ __launch_bounds__(256, 8) void chirplet_kernel(
    const float* __restrict__ x,
    const float* __restrict__ W,
    const float* __restrict__ Wc,
    const float* __restrict__ S,
    const float* __restrict__ T,
    const float* __restrict__ F,
    const float* __restrict__ bias,
    float* __restrict__ out)
{
    // R17: R14 structure (the 68.7us best) with ONE change: chirplet coeffs are
    // stored PRE-DUPLICATED in LDS ({a,a,b,b} / {c,c,d,d} / {lw,lw}) so the inner
    // loop's b128/b64 reads feed v_pk_fma_f32 as even-aligned pairs with ZERO
    // broadcast v_movs. R14 busy back-solve: 61 cyc/unit vs 56 theoretical --
    // the 5-cyc gap is exactly the 2.5 splat movs/unit this removes.
    // R16 lesson: prefetch restructure + sched_barrier regressed (load latency is
    // already covered by cross-block wave overlap) -- staging stays R14-style.
    __shared__ __align__(16) float ab_lds[ITILE * 32 * 4];   // 4 KB {a,a,b',b'}
    __shared__ __align__(16) float cd_lds[ITILE * 32 * 4];   // 4 KB {c2,c2,d2,d2}
    __shared__ __align__(16) float lw2_lds[ITILE * 32 * 2];  // 2 KB {lw,lw}
    __shared__ __align__(16) float x_lds[ITILE * XSTRIDE];   // 2.125 KB [i][b]
    __shared__ __align__(16) unsigned short sA_lds[BTILE * ASTRIDE]; // 5 KB silu bf16 [b][k]
    __shared__ __align__(16) unsigned short wB_lds[OTILE * ASTRIDE]; // 2.5 KB W bf16 [o][k]
    // total 19.6 KB -> still exactly 8 blocks/CU (8 x 20480 B = 160 KiB)

    const int tid  = threadIdx.x;
    const int wave = tid >> 6;
    const int lane = tid & 63;
    const int o0 = blockIdx.x * OTILE;
    const int b0 = blockIdx.y * BTILE;
    const int k0 = blockIdx.z * KCHUNK;

    const int oc = tid & 15;        // o col
    const int bq = tid >> 4;        // b quad: b = bq*4 + reg  (= MFMA C rows)

    const int xrow = tid >> 2;          // 0..63 (b)
    const int xq   = tid & 3;           // col pair 2*xq, 2*xq+1

    const int pol = tid & 31;           // o 0..31
    const int pi  = tid >> 5;           // i 0..7

    const float LOG2E = 1.4426950408889634f;
    const float GK    = 0.8493218002880191f;   // sqrt(0.5*log2(e))

    v2f acc2[2][2] = {{{0.f,0.f},{0.f,0.f}},{{0.f,0.f},{0.f,0.f}}};

    for (int c = 0; c < NCHUNKS; ++c) {
        const int ib = k0 + c * ITILE;

        // ---- stage x tile: x fp32 -> x_lds[i][b]; silu bf16 -> sA_lds[b][k]
        {
            const float2 v = *(const float2*)(x + (size_t)(b0 + xrow) * IN_ + ib + xq * 2);
            const float xf[2] = { v.x, v.y };
            unsigned int packed = 0;
            #pragma unroll
            for (int j = 0; j < 2; ++j) {
                const int col = xq * 2 + j;
                float xv  = xf[j];
                float sig = fast_rcp(1.0f + fast_exp2(-xv * LOG2E));
                x_lds[col * XSTRIDE + xrow] = xv;
                packed |= (unsigned int)f2bf(xv * sig) << (16 * j);
            }
            *(unsigned int*)&sA_lds[xrow * ASTRIDE + c * 8 + xq * 2] = packed;
        }

        // ---- stage params (32 o x 8 i): chirplet coeffs (pre-duplicated) + W bf16
        {
            const size_t go = (size_t)(o0 + pol) * IN_ + ib + pi;
            const float s  = S[go];
            const float t  = T[go];
            const float f  = F[go];
            const float w  = W[go];
            const float wc = Wc[go];
            const float rs = fast_rcp(s);
            const float a  = f * rs;                       // revolutions per x
            const float bp = -a * t + (wc < 0.0f ? 0.5f : 0.0f);  // phase + sign(Wc)
            const float c2 = rs * GK;
            const float d2 = -t * rs * GK;
            const float lg = fast_log2(fabsf(wc));
            const f32x4 abv = { a, a, bp, bp };
            const f32x4 cdv = { c2, c2, d2, d2 };
            const v2f   lwv = { lg, lg };
            *(f32x4*)&ab_lds[(pi * 32 + pol) * 4] = abv;
            *(f32x4*)&cd_lds[(pi * 32 + pol) * 4] = cdv;
            *(v2f*)&lw2_lds[(pi * 32 + pol) * 2] = lwv;
            wB_lds[pol * ASTRIDE + c * 8 + pi] = f2bf(w);
        }
        __syncthreads();

        // ---- compute: chirplet only (silu*W moved to MFMA)
        #pragma unroll 4
        for (int i = 0; i < ITILE; ++i) {
            const f32x4 ab[2] = {
                *(const f32x4*)&ab_lds[(i * 32 + oc) * 4],
                *(const f32x4*)&ab_lds[(i * 32 + oc + 16) * 4] };
            const f32x4 cd[2] = {
                *(const f32x4*)&cd_lds[(i * 32 + oc) * 4],
                *(const f32x4*)&cd_lds[(i * 32 + oc + 16) * 4] };
            const v2f lwp[2] = {
                *(const v2f*)&lw2_lds[(i * 32 + oc) * 2],
                *(const v2f*)&lw2_lds[(i * 32 + oc + 16) * 2] };
            const v2f* xp = (const v2f*)&x_lds[i * XSTRIDE + bq * 4];
            const v2f xk2[2] = { xp[0], xp[1] };
            #pragma unroll
            for (int o = 0; o < 2; ++o) {
                const v2f aa = __builtin_shufflevector(ab[o], ab[o], 0, 1);
                const v2f bb = __builtin_shufflevector(ab[o], ab[o], 2, 3);
                const v2f cc = __builtin_shufflevector(cd[o], cd[o], 0, 1);
                const v2f dd = __builtin_shufflevector(cd[o], cd[o], 2, 3);
                const v2f lwv = lwp[o];
                #pragma unroll
                for (int p = 0; p < 2; ++p) {
                    v2f rev = PKFMA(aa, xk2[p], bb);       // phase (revs)
                    v2f u   = PKFMA(cc, xk2[p], dd);       // GK*(x-t)/s
                    v2f arg = PKFMA(-u, u, lwv);           // lw - u^2
                    v2f co, e;
                    co.x = fast_cos_rev(rev.x);
                    co.y = fast_cos_rev(rev.y);
                    e.x  = fast_exp2(arg.x);
                    e.y  = fast_exp2(arg.y);
                    acc2[o][p] = PKFMA(co, e, acc2[o][p]); // chirplet
                }
            }
        }
        __syncthreads();
    }

    // ---- silu*W via matrix pipe: D[b][o] = sum_k silu[b][k] * W[o][k]
    const int q8 = (lane >> 4) * 8;
    const s16x8 af  = *(const s16x8*)&sA_lds[(wave * 16 + (lane & 15)) * ASTRIDE + q8];
    const s16x8 bf0 = *(const s16x8*)&wB_lds[(lane & 15) * ASTRIDE + q8];
    const s16x8 bf1 = *(const s16x8*)&wB_lds[((lane & 15) + 16) * ASTRIDE + q8];
    const f32x4 mz = { 0.f, 0.f, 0.f, 0.f };
    const f32x4 m0 = __builtin_amdgcn_mfma_f32_16x16x32_bf16(af, bf0, mz, 0, 0, 0);
    const f32x4 m1 = __builtin_amdgcn_mfma_f32_16x16x32_bf16(af, bf1, mz, 0, 0, 0);

    // ---- epilogue: chirplet acc + MFMA acc (same C-layout) + bias, atomic add
    const float badd[2] = { (blockIdx.z == 0) ? bias[o0 + oc] : 0.0f,
                            (blockIdx.z == 0) ? bias[o0 + oc + 16] : 0.0f };
    #pragma unroll
    for (int o = 0; o < 2; ++o) {
        #pragma unroll
        for (int p = 0; p < 2; ++p) {
            #pragma unroll
            for (int j = 0; j < 2; ++j) {
                const int reg = p * 2 + j;
                const int b = b0 + bq * 4 + reg;
                float* dst = &out[(size_t)b * OUT_ + o0 + oc + o * 16];
                const float mm = (o == 0) ? m0[reg] : m1[reg];
                const float val = (j == 0 ? acc2[o][p].x : acc2[o][p].y) + mm + badd[o];
#if defined(__HIP_DEVICE_COMPILE__)
                unsafeAtomicAdd(dst, val);   // HW global_atomic_add_f32
#else
                atomicAdd(dst, val);
#endif
            }
        }
    }
}

extern "C" void kernel_launch(void* const* d_in, const int* in_sizes, int n_in,
                              void* d_out, int out_size, void* d_ws, size_t ws_size,
                              hipStream_t stream) {
    const float* x    = (const float*)d_in[0];
    const float* W    = (const float*)d_in[1];
    const float* Wc   = (const float*)d_in[2];
    const float* S    = (const float*)d_in[3];
    const float* T    = (const float*)d_in[4];
    const float* F    = (const float*)d_in[5];
    const float* bias = (const float*)d_in[6];
    float* out = (float*)d_out;

    // d_out is poisoned before every launch; atomics need zeroed destination
    hipMemsetAsync(out, 0, (size_t)out_size * sizeof(float), stream);

    dim3 grid(OUT_ / OTILE, B_ / BTILE, KSPLIT);   // 16 x 16 x 16 = 4096 blocks
    chirplet_kernel<<<grid, 256, 0, stream>>>(x, W, Wc, S, T, F, bias, out);
}

// Round 3
// 129.201 us; speedup vs baseline: 1.0076x; 1.0076x over previous
//
#include <hip/hip_runtime.h>
#include <hip/hip_bf16.h>

#define B_ 1024
#define IN_ 512
#define OUT_ 512
#define BTILE 128
#define OTILE 32
#define ITILE 8
#define KSPLIT 16
#define KCHUNK (IN_ / KSPLIT)          // 32 i's per block
#define NCHUNKS (KCHUNK / ITILE)       // 4 staging chunks
#define P4STRIDE 128  // 32 o * 4 words; b128 writes/reads 2-way (free)
#define PLSTRIDE 32   // lw: [i][o], reads conflict-free
#define XSTRIDE 132   // BTILE + 4 pad
#define SASTRIDE 8    // sA row = 8 bf16 = 16 B (b128-aligned frag reads, 2-way free)

typedef float v2f   __attribute__((ext_vector_type(2)));
typedef float f32x4 __attribute__((ext_vector_type(4)));
typedef short s16x8 __attribute__((ext_vector_type(8)));   // 8 bf16 = 4 VGPRs
#define PKFMA(a, b, c) __builtin_elementwise_fma((v2f)(a), (v2f)(b), (v2f)(c))

__device__ __forceinline__ unsigned short f2bf(float f) {
    union { float f; unsigned int u; } v; v.f = f;
    unsigned int b = v.u + 0x7FFFu + ((v.u >> 16) & 1u);   // RNE
    return (unsigned short)(b >> 16);
}
__device__ __forceinline__ float fast_exp2(float x) {
#if __has_builtin(__builtin_amdgcn_exp2f)
    return __builtin_amdgcn_exp2f(x);
#else
    return __exp2f(x);
#endif
}
__device__ __forceinline__ float fast_log2(float x) {
#if __has_builtin(__builtin_amdgcn_logf)
    return __builtin_amdgcn_logf(x);
#else
    return __log2f(x);
#endif
}
__device__ __forceinline__ float fast_cos_rev(float x) {  // cos(2*pi*x), revolutions
#if __has_builtin(__builtin_amdgcn_cosf)
    return __builtin_amdgcn_cosf(x);
#else
    return __cosf(x * 6.2831853071795864f);
#endif
}
__device__ __forceinline__ float fast_rcp(float x) {
#if __has_builtin(__builtin_amdgcn_rcpf)
    return __builtin_amdgcn_rcpf(x);
#else
    return 1.0f / x;
#endif
}

__global__ __launch_bounds__(256, 8) void chirplet_kernel(
    const float* __restrict__ x,
    const float* __restrict__ W,
    const float* __restrict__ Wc,
    const float* __restrict__ S,
    const float* __restrict__ T,
    const float* __restrict__ F,
    const float* __restrict__ bias,
    float* __restrict__ out)
{
    // R18: raise arithmetic intensity per LDS byte. R14 sat at ~75% VALU issue AND
    // ~80% LDS delivery (128 B/clk/CU) simultaneously; R17 proved adding LDS bytes
    // is the wrong direction. Here NB doubles 4->8 (BTILE 128, each wave owns two
    // 16-row MFMA tiles): coefficient LDS bytes per unit halve -> LDS pipe ~60%.
    //  - grid 2048 = exactly 8 blocks/CU, one uniform round (kills dispatch tail)
    //  - silu*W via per-chunk K=8 micro-MFMA (k packed in lane-group 0, lanes>=16
    //    zero); MFMA is idle anyway, and sA shrinks to [128][8] bf16 = 2 KB
    //  - coeffs stay R14-format (splat movs cheaper than LDS bytes, per R17)
    __shared__ __align__(16) float p4_lds[ITILE * P4STRIDE];   // 4 KB {a,b',c2,d2}
    __shared__ __align__(16) float plw_lds[ITILE * PLSTRIDE];  // 1 KB log2|Wc|
    __shared__ __align__(16) float x_lds[ITILE * XSTRIDE];     // 4.125 KB [i][b]
    __shared__ __align__(16) unsigned short sA_lds[BTILE * SASTRIDE]; // 2 KB silu bf16 [b][k8]
    __shared__ __align__(16) unsigned short wB_lds[OTILE * SASTRIDE]; // 0.5 KB W bf16 [o][k8]
    // total ~11.9 KB -> 8 blocks/CU (wave-cap bound)

    const int tid  = threadIdx.x;
    const int wave = tid >> 6;
    const int lane = tid & 63;
    const int o0 = blockIdx.x * OTILE;
    const int b0 = blockIdx.y * BTILE;
    const int k0 = blockIdx.z * KCHUNK;

    const int oc = lane & 15;       // o col (MFMA C col)
    const int lq = lane >> 4;       // quad within wave; b = wave*32 + h*16 + lq*4 + reg

    const int xrow = tid >> 1;          // 0..127 (b)
    const int xq   = tid & 1;           // col quad: 4*xq .. 4*xq+3

    const int pol = tid & 31;           // o 0..31
    const int pi  = tid >> 5;           // i 0..7

    const float LOG2E = 1.4426950408889634f;
    const float GK    = 0.8493218002880191f;   // sqrt(0.5*log2(e))

    // acc2[o2][h*2+p]: b = wave*32 + h*16 + lq*4 + p*2 + j ; o = o0 + oc + o2*16
    v2f acc2[2][4] = {{{0.f,0.f},{0.f,0.f},{0.f,0.f},{0.f,0.f}},
                      {{0.f,0.f},{0.f,0.f},{0.f,0.f},{0.f,0.f}}};

    const int xb = wave * 32 + lq * 4;

    for (int c = 0; c < NCHUNKS; ++c) {
        const int ib = k0 + c * ITILE;

        // ---- stage x tile: x fp32 -> x_lds[i][b]; silu bf16 -> sA_lds[b][k]
        {
            const float4 v = *(const float4*)(x + (size_t)(b0 + xrow) * IN_ + ib + xq * 4);
            const float xf[4] = { v.x, v.y, v.z, v.w };
            unsigned int pk[2] = { 0u, 0u };
            #pragma unroll
            for (int j = 0; j < 4; ++j) {
                const int col = xq * 4 + j;
                const float xv  = xf[j];
                const float sig = fast_rcp(1.0f + fast_exp2(-xv * LOG2E));
                x_lds[col * XSTRIDE + xrow] = xv;
                pk[j >> 1] |= (unsigned int)f2bf(xv * sig) << (16 * (j & 1));
            }
            *(uint2*)&sA_lds[xrow * SASTRIDE + xq * 4] = make_uint2(pk[0], pk[1]);
        }

        // ---- stage params (32 o x 8 i): chirplet coeffs + W bf16 (8 k) for MFMA
        {
            const size_t go = (size_t)(o0 + pol) * IN_ + ib + pi;
            const float s  = S[go];
            const float t  = T[go];
            const float f  = F[go];
            const float wc = Wc[go];
            const float rs = fast_rcp(s);
            const float a  = f * rs;                       // revolutions per x
            float4 p0;
            p0.x = a;
            p0.y = -a * t + (wc < 0.0f ? 0.5f : 0.0f);     // phase + sign(Wc)
            p0.z = rs * GK;
            p0.w = -t * rs * GK;
            *(float4*)&p4_lds[pi * P4STRIDE + pol * 4] = p0;
            plw_lds[pi * PLSTRIDE + pol] = fast_log2(fabsf(wc));
            // W: 32 o x 8 k, one bf16 per thread, coalesced in k
            const int wo = tid >> 3, wk = tid & 7;
            wB_lds[wo * SASTRIDE + wk] = f2bf(W[(size_t)(o0 + wo) * IN_ + ib + wk]);
        }
        __syncthreads();

        // ---- per-chunk micro-GEMM on matrix pipe: K=8 valid (lane-group 0), rest 0
        {
            s16x8 af0 = {0,0,0,0,0,0,0,0}, af1 = af0, bfA = af0, bfB = af0;
            if (lane < 16) {
                af0 = *(const s16x8*)&sA_lds[(wave * 32 +      (lane & 15)) * SASTRIDE];
                af1 = *(const s16x8*)&sA_lds[(wave * 32 + 16 + (lane & 15)) * SASTRIDE];
                bfA = *(const s16x8*)&wB_lds[(lane & 15) * SASTRIDE];
                bfB = *(const s16x8*)&wB_lds[(16 + (lane & 15)) * SASTRIDE];
            }
            const f32x4 mz = { 0.f, 0.f, 0.f, 0.f };
            const f32x4 m00 = __builtin_amdgcn_mfma_f32_16x16x32_bf16(af0, bfA, mz, 0, 0, 0);
            const f32x4 m01 = __builtin_amdgcn_mfma_f32_16x16x32_bf16(af0, bfB, mz, 0, 0, 0);
            const f32x4 m10 = __builtin_amdgcn_mfma_f32_16x16x32_bf16(af1, bfA, mz, 0, 0, 0);
            const f32x4 m11 = __builtin_amdgcn_mfma_f32_16x16x32_bf16(af1, bfB, mz, 0, 0, 0);
            // fold into chirplet accs (identical C-layout: col=oc, row=lq*4+reg)
            acc2[0][0] += (v2f){ m00[0], m00[1] };  acc2[0][1] += (v2f){ m00[2], m00[3] };
            acc2[0][2] += (v2f){ m10[0], m10[1] };  acc2[0][3] += (v2f){ m10[2], m10[3] };
            acc2[1][0] += (v2f){ m01[0], m01[1] };  acc2[1][1] += (v2f){ m01[2], m01[3] };
            acc2[1][2] += (v2f){ m11[0], m11[1] };  acc2[1][3] += (v2f){ m11[2], m11[3] };
        }

        // ---- compute: chirplet (8 b x 2 o per thread)
        #pragma unroll 2
        for (int i = 0; i < ITILE; ++i) {
            const float4 abcd[2] = {
                *(const float4*)&p4_lds[i * P4STRIDE + oc * 4],
                *(const float4*)&p4_lds[i * P4STRIDE + (oc + 16) * 4] };
            const float lw[2] = {
                plw_lds[i * PLSTRIDE + oc],
                plw_lds[i * PLSTRIDE + oc + 16] };
            const f32x4 xh0 = *(const f32x4*)&x_lds[i * XSTRIDE + xb];
            const f32x4 xh1 = *(const f32x4*)&x_lds[i * XSTRIDE + xb + 16];
            const v2f xk2[4] = {
                __builtin_shufflevector(xh0, xh0, 0, 1),
                __builtin_shufflevector(xh0, xh0, 2, 3),
                __builtin_shufflevector(xh1, xh1, 0, 1),
                __builtin_shufflevector(xh1, xh1, 2, 3) };
            #pragma unroll
            for (int o = 0; o < 2; ++o) {
                const v2f aa = { abcd[o].x, abcd[o].x };
                const v2f bb = { abcd[o].y, abcd[o].y };
                const v2f cc = { abcd[o].z, abcd[o].z };
                const v2f dd = { abcd[o].w, abcd[o].w };
                const v2f lwv = { lw[o], lw[o] };
                #pragma unroll
                for (int p = 0; p < 4; ++p) {
                    v2f rev = PKFMA(aa, xk2[p], bb);       // phase (revs)
                    v2f u   = PKFMA(cc, xk2[p], dd);       // GK*(x-t)/s
                    v2f arg = PKFMA(-u, u, lwv);           // lw - u^2
                    v2f co, e;
                    co.x = fast_cos_rev(rev.x);
                    co.y = fast_cos_rev(rev.y);
                    e.x  = fast_exp2(arg.x);
                    e.y  = fast_exp2(arg.y);
                    acc2[o][p] = PKFMA(co, e, acc2[o][p]); // chirplet
                }
            }
        }
        __syncthreads();
    }

    // ---- epilogue: acc (chirplet + micro-GEMM already fused) + bias, atomic add
    const float badd[2] = { (blockIdx.z == 0) ? bias[o0 + oc] : 0.0f,
                            (blockIdx.z == 0) ? bias[o0 + oc + 16] : 0.0f };
    #pragma unroll
    for (int o = 0; o < 2; ++o) {
        #pragma unroll
        for (int hp = 0; hp < 4; ++hp) {
            const int h = hp >> 1, p = hp & 1;
            #pragma unroll
            for (int j = 0; j < 2; ++j) {
                const int b = b0 + wave * 32 + h * 16 + lq * 4 + p * 2 + j;
                float* dst = &out[(size_t)b * OUT_ + o0 + oc + o * 16];
                const float val = (j == 0 ? acc2[o][hp].x : acc2[o][hp].y) + badd[o];
#if defined(__HIP_DEVICE_COMPILE__)
                unsafeAtomicAdd(dst, val);   // HW global_atomic_add_f32
#else
                atomicAdd(dst, val);
#endif
            }
        }
    }
}

extern "C" void kernel_launch(void* const* d_in, const int* in_sizes, int n_in,
                              void* d_out, int out_size, void* d_ws, size_t ws_size,
                              hipStream_t stream) {
    const float* x    = (const float*)d_in[0];
    const float* W    = (const float*)d_in[1];
    const float* Wc   = (const float*)d_in[2];
    const float* S    = (const float*)d_in[3];
    const float* T    = (const float*)d_in[4];
    const float* F    = (const float*)d_in[5];
    const float* bias = (const float*)d_in[6];
    float* out = (float*)d_out;

    // d_out is poisoned before every launch; atomics need zeroed destination
    hipMemsetAsync(out, 0, (size_t)out_size * sizeof(float), stream);

    dim3 grid(OUT_ / OTILE, B_ / BTILE, KSPLIT);   // 16 x 8 x 16 = 2048 blocks = 8/CU
    chirplet_kernel<<<grid, 256, 0, stream>>>(x, W, Wc, S, T, F, bias, out);
}